// Round 20
// baseline (229.296 us; speedup 1.0000x reference)
//
#include <hip/hip_runtime.h>
#include <cstdint>

typedef unsigned int u32;
typedef unsigned long long u64;

#define NCLS 21
#define TOPK 200
#define MAXP 8732
#define CAND 384
#define NXCD 8
#define NREG 9   // ceil((MAXP/4)/256)

// Scores: XLA:GPU(gfx950) softmax emulation — exp(x) = v_exp_f32(x*log2e),
// butterfly-tree sum. Everything else stepwise IEEE f32, no fusion.
// ALL numeric values bit-identical to the round-13..19 passing kernels.
#pragma clang fp contract(off)

__device__ __forceinline__ float tri_expf(float x) {
  float t = __fmul_rn(x, 1.4426950408889634f);
  return __builtin_amdgcn_exp2f(t);               // v_exp_f32
}

__device__ __forceinline__ float butterfly_sum21(const float* e) {
  float v[32];
#pragma unroll
  for (int k = 0; k < NCLS; ++k) v[k] = e[k];
#pragma unroll
  for (int k = NCLS; k < 32; ++k) v[k] = 0.0f;
  float a[16], b[8], c4[4], d2[2];
#pragma unroll
  for (int i = 0; i < 16; ++i) a[i] = __fadd_rn(v[i], v[i + 16]);
#pragma unroll
  for (int i = 0; i < 8; ++i) b[i] = __fadd_rn(a[i], a[i + 8]);
#pragma unroll
  for (int i = 0; i < 4; ++i) c4[i] = __fadd_rn(b[i], b[i + 4]);
#pragma unroll
  for (int i = 0; i < 2; ++i) d2[i] = __fadd_rn(c4[i], c4[i + 2]);
  return __fadd_rn(d2[0], d2[1]);
}

__device__ __forceinline__ void softmax_row(const float* __restrict__ row,
                                            float* e, float& mx, float& S) {
  float xs[NCLS];
#pragma unroll
  for (int k = 0; k < NCLS; ++k) xs[k] = row[k];
  mx = xs[0];
#pragma unroll
  for (int k = 1; k < NCLS; ++k) mx = fmaxf(mx, xs[k]);
#pragma unroll
  for (int k = 0; k < NCLS; ++k) e[k] = tri_expf(__fsub_rn(xs[k], mx));
  S = butterfly_sum21(e);
}

__device__ __forceinline__ int swz_task(int bid, int nwg) {
  if ((nwg % NXCD) == 0) return (bid % NXCD) * (nwg / NXCD) + bid / NXCD;
  return bid;
}

// wave-aggregated histogram add: one LDS atomic per distinct 8-bit digit per
// wave (counts identical to per-lane atomicAdd; order-invariant integer sums)
__device__ __forceinline__ void hist_add(u32* hist, u32 d, bool act, int lane) {
  u64 m = __ballot((int)act);
  if (m == 0) return;
#pragma unroll
  for (int bit = 0; bit < 8; ++bit) {
    u64 vb = __ballot((int)((d >> bit) & 1u));
    m &= ((d >> bit) & 1u) ? vb : ~vb;
  }
  if (act) {
    int leader = __ffsll((long long)m) - 1;
    if (lane == leader) atomicAdd(&hist[d], (u32)__popcll(m));
  }
}

// ---------------- prep2: transposed f32 probs (f64 rcp-mul == __fdiv_rn bits)
__global__ __launch_bounds__(256) void prep2_k(const float* __restrict__ conf,
                                               float* __restrict__ probs_t,
                                               int B, int P) {
  int gid = blockIdx.x * 256 + threadIdx.x;
  if (gid >= B * P) return;
  int b = gid / P, p = gid - b * P;
  float e[NCLS], mx, S;
  softmax_row(conf + (size_t)gid * NCLS, e, mx, S);
  double invS = 1.0 / (double)S;
#pragma unroll
  for (int c = 1; c < NCLS; ++c)
    probs_t[((size_t)b * (NCLS - 1) + (c - 1)) * P + p] =
        (float)((double)e[c] * invS);
}

// ---------------- fused select + NMS, DS-pipe-lean version
__global__ __launch_bounds__(256) void fused5_k(const float* __restrict__ loc,
                                                const float* __restrict__ priors,
                                                const float* __restrict__ probs_t,
                                                float* __restrict__ out, int B, int P) {
  __shared__ __align__(16) unsigned char smem[16096];
  u32* hist = (u32*)smem;                          // [0,1024)    (dead after radix)
  u64* ckey = (u64*)(smem + 1024);                 // [1024,4096) (dead after decode)
  int* srt  = (int*)(smem + 4096);                 // [4096,4896) (dead after decode)
  float4* bxp = (float4*)(smem + 4896);            // [4896,8096)
  float* vals  = (float*)(smem + 8096);            // [8096,8896)
  float* sarea = (float*)(smem + 8896);            // [8896,9696)
  u64 (*msk)[4] = (u64 (*)[4])(smem + 9696);       // [9696,16096)
  float* st = (float*)smem;                        // overlay [0,4000) after decode
  __shared__ u32 s_prefix;
  __shared__ int s_K, s_cnt, s_nv;
  __shared__ u64 s_kp[4];

  const int tid = threadIdx.x;
  const int lane = tid & 63;
  const int task = swz_task(blockIdx.x, gridDim.x);
  const int b = task / (NCLS - 1), cm1 = task - b * (NCLS - 1);
  const int n4 = P >> 2;                            // P % 4 == 0 (host-guarded)
  const float4* base4 = (const float4*)(probs_t + (size_t)task * P);

  if (cm1 == 0) {   // zero the background-class rows of this image
    float* bg = out + (size_t)b * (NCLS * TOPK * 5);
    for (int i = tid; i < TOPK * 5; i += 256) bg[i] = 0.0f;
  }
  hist[tid] = 0;
  if (tid == 0) { s_cnt = 0; s_nv = TOPK; }
  __syncthreads();

  // ---- single streaming read -> registers; pass-0 histogram (wave-aggregated)
  u32 v[NREG * 4];
#pragma unroll
  for (int k = 0; k < NREG; ++k) {
    int i4 = tid + k * 256;
    bool ok = (i4 < n4);
    float4 f = ok ? base4[i4] : make_float4(0.f, 0.f, 0.f, 0.f);
    v[4 * k + 0] = __float_as_uint(f.x);
    v[4 * k + 1] = __float_as_uint(f.y);
    v[4 * k + 2] = __float_as_uint(f.z);
    v[4 * k + 3] = __float_as_uint(f.w);
#pragma unroll
    for (int j = 0; j < 4; ++j)
      hist_add(hist, v[4 * k + j] >> 24, ok, lane);
  }
  __syncthreads();

  u32 prefix = 0; int K = TOPK;
  for (int pass = 0; pass < 4; ++pass) {
    int shift = 24 - 8 * pass;
    if (pass > 0) {
      u32 known = 0xFFFFFFFFu << (32 - 8 * pass);
      hist[tid] = 0;
      __syncthreads();
#pragma unroll
      for (int k = 0; k < NREG; ++k) {
        bool ok = (tid + k * 256 < n4);
#pragma unroll
        for (int j = 0; j < 4; ++j) {
          u32 val = v[4 * k + j];
          hist_add(hist, (val >> shift) & 0xFFu, ok && (val & known) == prefix, lane);
        }
      }
      __syncthreads();
    }
    // single-wave suffix scan: hist[t] = count(digit >= t)
    if (tid < 64) {
      int l = tid;
      u32 c0 = hist[4 * l], c1 = hist[4 * l + 1], c2 = hist[4 * l + 2], c3 = hist[4 * l + 3];
      u32 s3 = c3, s2 = c2 + s3, s1 = c1 + s2, s0 = c0 + s1;
      u32 tot = s0, acc = tot;
#pragma unroll
      for (int off = 1; off < 64; off <<= 1) {
        u32 o = __shfl_down(acc, off);
        if (l + off < 64) acc += o;
      }
      u32 upper = acc - tot;
      hist[4 * l]     = s0 + upper;
      hist[4 * l + 1] = s1 + upper;
      hist[4 * l + 2] = s2 + upper;
      hist[4 * l + 3] = s3 + upper;
    }
    __syncthreads();
    u32 ge = hist[tid];
    u32 gt = (tid == 255) ? 0u : hist[tid + 1];
    if (ge >= (u32)K && gt < (u32)K) { s_prefix = prefix | ((u32)tid << shift); s_K = K - (int)gt; }
    __syncthreads();
    prefix = s_prefix; K = s_K;
    __syncthreads();
  }
  const u32 T = prefix;

  // ---- compact candidates (bits >= T): ballot-aggregated (set identical;
  // slot order differs but rank-by-count re-sorts exactly)
#pragma unroll
  for (int k = 0; k < NREG; ++k) {
    int i4 = tid + k * 256;
    bool ok = (i4 < n4);
#pragma unroll
    for (int j = 0; j < 4; ++j) {
      u32 val = v[4 * k + j];
      bool pred = ok && (val >= T);
      u64 bm = __ballot((int)pred);
      if (bm) {
        int leader = __ffsll((long long)bm) - 1;
        int base = 0;
        if (lane == leader) base = atomicAdd(&s_cnt, (int)__popcll(bm));
        base = __shfl(base, leader);
        if (pred) {
          int slot = base + (int)__popcll(bm & ((1ull << lane) - 1ull));
          if (slot < CAND)
            ckey[slot] = ((u64)val << 32) | (u64)(0xFFFFFFFFu - (u32)(4 * i4 + j));
        }
      }
    }
  }
  __syncthreads();
  int cnt = s_cnt; if (cnt > CAND) cnt = CAND;

  // ---- exact rank by counting (broadcast reads)
  for (int i = tid; i < cnt; i += 256) {
    u64 k = ckey[i]; int r = 0;
    for (int j = 0; j < cnt; ++j) r += (ckey[j] > k) ? 1 : 0;
    if (r < TOPK) srt[r] = i;
  }
  __syncthreads();

  // ---- decode top-200 (bit-identical op sequence) + area hoist
  if (tid < TOPK) {
    u64 key = ckey[srt[tid]];
    float vv = __uint_as_float((u32)(key >> 32));
    int p = (int)(0xFFFFFFFFu - (u32)(key & 0xFFFFFFFFull));
    float4 lp = ((const float4*)loc)[(size_t)b * P + p];
    float4 pr = ((const float4*)priors)[p];
    float tx = __fmul_rn(__fmul_rn(lp.x, 0.1f), pr.z);
    float ty = __fmul_rn(__fmul_rn(lp.y, 0.1f), pr.w);
    float cx = __fadd_rn(pr.x, tx);
    float cy = __fadd_rn(pr.y, ty);
    float w = __fmul_rn(pr.z, expf(__fmul_rn(lp.z, 0.2f)));
    float h = __fmul_rn(pr.w, expf(__fmul_rn(lp.w, 0.2f)));
    float hw = __fmul_rn(w, 0.5f), hh = __fmul_rn(h, 0.5f);
    float x1 = __fsub_rn(cx, hw), y1 = __fsub_rn(cy, hh);
    float x2 = __fadd_rn(cx, hw), y2 = __fadd_rn(cy, hh);
    bxp[tid] = make_float4(x1, y1, x2, y2);
    vals[tid] = vv;
    sarea[tid] = __fmul_rn(__fsub_rn(x2, x1), __fsub_rn(y2, y1));  // ref area bits
    if (!(vv > 0.01f)) atomicMin(&s_nv, tid);
  }
  __syncthreads();
  const int n = s_nv;

  // ---- IoU mask matrix, uniform-j broadcast loop (wave w starts at 64w+1;
  // only j > tid bits are ever consulted by the greedy scan)
  {
    const int w = tid >> 6;
    const bool havrow = (tid < n);
    float rx1 = 0.f, ry1 = 0.f, rx2 = 0.f, ry2 = 0.f, ar = 0.f;
    if (havrow) {
      float4 bb = bxp[tid];
      rx1 = bb.x; ry1 = bb.y; rx2 = bb.z; ry2 = bb.w;
      ar = sarea[tid];
    }
    u64 m0 = 0, m1 = 0, m2 = 0, m3 = 0;
    for (int j = (w << 6) + 1; j < n; ++j) {
      float4 bj = bxp[j];          // LDS broadcast (uniform address)
      float aj = sarea[j];         // LDS broadcast
      float ww = fmaxf(__fsub_rn(fminf(rx2, bj.z), fmaxf(rx1, bj.x)), 0.0f);
      float hh = fmaxf(__fsub_rn(fminf(ry2, bj.w), fmaxf(ry1, bj.y)), 0.0f);
      float inter = __fmul_rn(ww, hh);
      float den = __fsub_rn(__fadd_rn(ar, aj), inter);
      float iou = __fdiv_rn(inter, den);   // NaN (0/0) -> comparison false
      if (havrow && tid < j && iou > 0.45f) {
        u64 bit = 1ull << (j & 63);
        int w4 = j >> 6;
        if (w4 == 0) m0 |= bit; else if (w4 == 1) m1 |= bit;
        else if (w4 == 2) m2 |= bit; else m3 |= bit;
      }
    }
    if (havrow) { msk[tid][0] = m0; msk[tid][1] = m1; msk[tid][2] = m2; msk[tid][3] = m3; }
  }
  __syncthreads();

  // ---- scalar greedy scan on wave 0 only; broadcast keep-words via LDS
  if (tid < 64) {
    u64 remv0 = 0, remv1 = 0, remv2 = 0, remv3 = 0;
    u64 kp0 = 0, kp1 = 0, kp2 = 0, kp3 = 0;
    int i = 0;
#define SCAN_WORD(KW, RW)                                              \
    for (int bpos = 0; bpos < 64 && i < n; ++bpos, ++i) {              \
      if (!((RW >> bpos) & 1ull)) {                                    \
        KW |= 1ull << bpos;                                            \
        remv0 |= msk[i][0]; remv1 |= msk[i][1];                        \
        remv2 |= msk[i][2]; remv3 |= msk[i][3];                        \
      }                                                                \
    }
    SCAN_WORD(kp0, remv0)
    SCAN_WORD(kp1, remv1)
    SCAN_WORD(kp2, remv2)
    SCAN_WORD(kp3, remv3)
#undef SCAN_WORD
    if (tid == 0) { s_kp[0] = kp0; s_kp[1] = kp1; s_kp[2] = kp2; s_kp[3] = kp3; }
  }
  __syncthreads();
  const u64 kp0 = s_kp[0], kp1 = s_kp[1], kp2 = s_kp[2], kp3 = s_kp[3];

  for (int i = tid; i < TOPK * 5; i += 256) st[i] = 0.0f;   // st overlays hist/ckey (dead)
  __syncthreads();
  if (tid < TOPK) {
    int w4 = tid >> 6, bpos = tid & 63;
    u64 kw = (w4 == 0) ? kp0 : (w4 == 1) ? kp1 : (w4 == 2) ? kp2 : kp3;
    if ((kw >> bpos) & 1ull) {
      int pos = (int)__popcll(kw & ((1ull << bpos) - 1ull));
      if (w4 > 0) pos += (int)__popcll(kp0);
      if (w4 > 1) pos += (int)__popcll(kp1);
      if (w4 > 2) pos += (int)__popcll(kp2);
      st[pos * 5 + 0] = vals[tid];
      float4 bb = bxp[tid];
      st[pos * 5 + 1] = bb.x;
      st[pos * 5 + 2] = bb.y;
      st[pos * 5 + 3] = bb.z;
      st[pos * 5 + 4] = bb.w;
    }
  }
  __syncthreads();
  float* op = out + (size_t)(b * NCLS + 1 + cm1) * (TOPK * 5);
  if (tid < TOPK * 5 / 4) ((float4*)op)[tid] = ((const float4*)st)[tid];
}

// ---------------- fused fallback (verified R13 kernel), used if ws tiny / odd P
__global__ __launch_bounds__(256) void fused_k(
    const float* __restrict__ loc, const float* __restrict__ conf,
    const float* __restrict__ priors, float* __restrict__ out, int B, int P) {
  __shared__ __align__(16) u32 sc[MAXP];
  __shared__ u64 ckey[CAND];
  __shared__ u32 hist[256];
  __shared__ int srt[TOPK];
  __shared__ float bx[TOPK][4];
  __shared__ float vals[TOPK];
  __shared__ __align__(16) float st[TOPK * 5];
  __shared__ u32 s_prefix;
  __shared__ int s_K, s_cnt, s_nv;
  __shared__ u64 s_kw[4];

  const int tid = threadIdx.x;
  const int task = blockIdx.x;
  const int b = task / (NCLS - 1), cm1 = task - b * (NCLS - 1);
  const int c = cm1 + 1;

  if (cm1 == 0) {
    float* bg = out + (size_t)b * (NCLS * TOPK * 5);
    for (int i = tid; i < TOPK * 5; i += 256) bg[i] = 0.0f;
  }
  for (int p = tid; p < P; p += 256) {
    float e[NCLS], mx, S;
    softmax_row(conf + ((size_t)b * P + p) * NCLS, e, mx, S);
    sc[p] = __float_as_uint(__fdiv_rn(e[c], S));
  }
  if (tid == 0) s_cnt = 0;
  __syncthreads();
  u32 prefix = 0; int K = TOPK;
  for (int pass = 0; pass < 4; ++pass) {
    int shift = 24 - 8 * pass;
    u32 known = (pass == 0) ? 0u : (0xFFFFFFFFu << (32 - 8 * pass));
    hist[tid] = 0;
    __syncthreads();
    for (int p = tid; p < P; p += 256) {
      u32 vv = sc[p];
      if ((vv & known) == prefix) atomicAdd(&hist[(vv >> shift) & 0xFFu], 1u);
    }
    __syncthreads();
    for (int off = 1; off < 256; off <<= 1) {
      u32 add = (tid + off < 256) ? hist[tid + off] : 0u;
      __syncthreads();
      hist[tid] += add;
      __syncthreads();
    }
    u32 ge = hist[tid];
    u32 gt = (tid == 255) ? 0u : hist[tid + 1];
    if (ge >= (u32)K && gt < (u32)K) { s_prefix = prefix | ((u32)tid << shift); s_K = K - (int)gt; }
    __syncthreads();
    prefix = s_prefix; K = s_K;
    __syncthreads();
  }
  const u32 T = prefix;
  for (int p = tid; p < P; p += 256) {
    u32 vv = sc[p];
    if (vv >= T) {
      int slot = atomicAdd(&s_cnt, 1);
      if (slot < CAND) ckey[slot] = ((u64)vv << 32) | (u64)(0xFFFFFFFFu - (u32)p);
    }
  }
  __syncthreads();
  int cnt = s_cnt; if (cnt > CAND) cnt = CAND;
  for (int i = tid; i < cnt; i += 256) {
    u64 k = ckey[i]; int r = 0;
    for (int j = 0; j < cnt; ++j) r += (ckey[j] > k) ? 1 : 0;
    if (r < TOPK) srt[r] = i;
  }
  if (tid == 0) s_nv = TOPK;
  __syncthreads();
  if (tid < TOPK) {
    u64 key = ckey[srt[tid]];
    float vv = __uint_as_float((u32)(key >> 32));
    int p = (int)(0xFFFFFFFFu - (u32)(key & 0xFFFFFFFFull));
    float4 lp = ((const float4*)loc)[(size_t)b * P + p];
    float4 pr = ((const float4*)priors)[p];
    float tx = __fmul_rn(__fmul_rn(lp.x, 0.1f), pr.z);
    float ty = __fmul_rn(__fmul_rn(lp.y, 0.1f), pr.w);
    float cx = __fadd_rn(pr.x, tx);
    float cy = __fadd_rn(pr.y, ty);
    float w = __fmul_rn(pr.z, expf(__fmul_rn(lp.z, 0.2f)));
    float h = __fmul_rn(pr.w, expf(__fmul_rn(lp.w, 0.2f)));
    float hw = __fmul_rn(w, 0.5f), hh = __fmul_rn(h, 0.5f);
    bx[tid][0] = __fsub_rn(cx, hw);
    bx[tid][1] = __fsub_rn(cy, hh);
    bx[tid][2] = __fadd_rn(cx, hw);
    bx[tid][3] = __fadd_rn(cy, hh);
    vals[tid] = vv;
    if (!(vv > 0.01f)) atomicMin(&s_nv, tid);
  }
  __syncthreads();
  if (tid < 64) {
    int lane = tid;
    float jx1[4], jy1[4], jx2[4], jy2[4], aj[4];
#pragma unroll
    for (int s = 0; s < 4; ++s) {
      int j = s * 64 + lane;
      if (j < TOPK) { jx1[s]=bx[j][0]; jy1[s]=bx[j][1]; jx2[s]=bx[j][2]; jy2[s]=bx[j][3]; }
      else { jx1[s]=0.f; jy1[s]=0.f; jx2[s]=0.f; jy2[s]=0.f; }
      aj[s] = __fmul_rn(__fsub_rn(jx2[s], jx1[s]), __fsub_rn(jy2[s], jy1[s]));
    }
    u32 keepn = 0;
    int n = s_nv;
    for (int i = 0; i < n; ++i) {
      float ix1 = bx[i][0], iy1 = bx[i][1], ix2 = bx[i][2], iy2 = bx[i][3];
      float ai = __fmul_rn(__fsub_rn(ix2, ix1), __fsub_rn(iy2, iy1));
      bool sup = false;
#pragma unroll
      for (int s = 0; s < 4; ++s) {
        float ww = fmaxf(__fsub_rn(fminf(ix2, jx2[s]), fmaxf(ix1, jx1[s])), 0.0f);
        float hh = fmaxf(__fsub_rn(fminf(iy2, jy2[s]), fmaxf(iy1, jy1[s])), 0.0f);
        float inter = __fmul_rn(ww, hh);
        float den = __fsub_rn(__fadd_rn(ai, aj[s]), inter);
        float iou = __fdiv_rn(inter, den);
        if (((keepn >> s) & 1u) && (iou > 0.45f)) sup = true;
      }
      if (!__any((int)sup)) { if (lane == (i & 63)) keepn |= 1u << (i >> 6); }
    }
    u64 w0 = __ballot((int)(keepn & 1u));
    u64 w1 = __ballot((int)((keepn >> 1) & 1u));
    u64 w2 = __ballot((int)((keepn >> 2) & 1u));
    u64 w3 = __ballot((int)((keepn >> 3) & 1u));
    if (lane == 0) { s_kw[0]=w0; s_kw[1]=w1; s_kw[2]=w2; s_kw[3]=w3; }
  }
  __syncthreads();
  for (int i = tid; i < TOPK * 5; i += 256) st[i] = 0.0f;
  __syncthreads();
  if (tid < TOPK) {
    int w = tid >> 6, bit = tid & 63;
    u64 kwv = s_kw[w];
    if ((kwv >> bit) & 1ull) {
      int pos = (int)__popcll(kwv & ((1ull << bit) - 1ull));
      for (int w2 = 0; w2 < w; ++w2) pos += (int)__popcll(s_kw[w2]);
      st[pos*5+0] = vals[tid];
      st[pos*5+1] = bx[tid][0];
      st[pos*5+2] = bx[tid][1];
      st[pos*5+3] = bx[tid][2];
      st[pos*5+4] = bx[tid][3];
    }
  }
  __syncthreads();
  float* op = out + (size_t)(b * NCLS + 1 + cm1) * (TOPK * 5);
  if (tid < TOPK * 5 / 4) ((float4*)op)[tid] = ((const float4*)st)[tid];
}

extern "C" void kernel_launch(void* const* d_in, const int* in_sizes, int n_in,
                              void* d_out, int out_size, void* d_ws, size_t ws_size,
                              hipStream_t stream) {
  const float* loc    = (const float*)d_in[0];
  const float* conf   = (const float*)d_in[1];
  const float* priors = (const float*)d_in[2];
  float* out = (float*)d_out;

  int P = in_sizes[2] / 4;              // 8732
  int B = in_sizes[0] / (P * 4);        // 128
  int tasks = B * (NCLS - 1);           // 2560
  int BP = B * P;

  size_t probB = (size_t)B * (NCLS - 1) * P * sizeof(float);    // ~89.4 MB

  if (ws_size >= probB && (P % 4) == 0 && P <= MAXP) {
    float* probs_t = (float*)d_ws;
    prep2_k<<<(BP + 255) / 256, 256, 0, stream>>>(conf, probs_t, B, P);
    fused5_k<<<tasks, 256, 0, stream>>>(loc, priors, probs_t, out, B, P);
  } else {
    fused_k<<<tasks, 256, 0, stream>>>(loc, conf, priors, out, B, P);
  }
}